// Round 2
// baseline (116.725 us; speedup 1.0000x reference)
//
#include <hip/hip_runtime.h>
#include <stdint.h>
#include <stdio.h>
#include <stdlib.h>
#include <unistd.h>
#include <math.h>

// ============================================================================
// QonvLayer: out[b, c2, j, k, l] (4, 32, 32, 32, 32) fp32.
// Only j,k,l < 16 nonzero. c2<16 -> circuit(weights1) on patch offsets
// (0,0,0),(1,1,0),(0,1,1),(1,0,1); c2>=16 -> circuit(weights2) on offsets
// (1,1,1),(0,0,1),(1,0,0),(0,1,0). Input index = (2j+dj, 2k+dk, 2l+dl).
//
// value = <Z_0> = 81-coefficient double-angle form:
//   <Z_0> = sum_{e in {0,1,2}^4} G[e] * prod_t v_t[e_t],
//   v_t = (1, cos(pi*min(1,y_t)), sin(pi*min(1,y_t)))
//
// R5 (this round): SINGLE fused kernel, 2048 blocks = (b, c2, j<16).
//  - Each block rebuilds G[81] for its weight set in LDS (redundant but
//    trivial: 128-thread butterfly evolution of U, ~11 barriers). Removes
//    the separate build_G dispatch, its graph-serialization gap, and the
//    g_G device-global round trip.
//  - Wave 0 (lanes 0..63, 100% active) computes the 64 active float4 cells,
//    stages them through LDS; all 256 threads then issue 2 coalesced float4
//    stores each (active slice j + zero slice j+16). Block count halved vs
//    R4 (no zero-only blocks).
//  - Math identical to the R3/R4-validated algebra (passed absmax 0.0039).
//
// Gate plan = _make_plan(1234) via the harness's own python (/proc/self/exe)
// + numpy (ground truth, validated round 3); C++ PCG64 replication fallback
// (known-suspect; +1000 sentinel on out[0] if python unavailable).
// ============================================================================

struct PlanArg {
    int n;
    // ops[i]: x = type (0=rot, 1=cnot)
    //         y = gate (0 RX,1 RY,2 RZ)   or ctrl wire
    //         z = wire                    or tgt wire
    //         w = weight flat index l*4+i or 0
    int4 ops[24];
};

// ---------------------------------------------------------------------------
// Fallback: host-side replication of numpy default_rng(1234) (emergency only)
// ---------------------------------------------------------------------------
typedef unsigned __int128 u128_t;

namespace nprng {

struct Pcg64 {
    u128_t state, inc;
    bool has32; uint32_t buf32;

    void step() {
        const u128_t MULT =
            ((u128_t)0x2360ed051fc65da4ULL << 64) | (u128_t)0x4385df649fccf645ULL;
        state = state * MULT + inc;
    }
    uint64_t next64() {
        step();
        uint64_t hi = (uint64_t)(state >> 64), lo = (uint64_t)state;
        unsigned rot = (unsigned)(hi >> 58);
        uint64_t v = hi ^ lo;
        return (v >> rot) | (v << ((64u - rot) & 63u));
    }
    uint32_t next32() {
        if (has32) { has32 = false; return buf32; }
        uint64_t n = next64();
        has32 = true; buf32 = (uint32_t)(n >> 32);
        return (uint32_t)n;
    }
    double rnd() {
        return (double)(next64() >> 11) * (1.0 / 9007199254740992.0);
    }
    uint32_t lemire32(uint32_t rng) {
        uint32_t rng_excl = rng + 1u;
        uint64_t m = (uint64_t)next32() * (uint64_t)rng_excl;
        uint32_t leftover = (uint32_t)m;
        if (leftover < rng_excl) {
            uint32_t threshold = (uint32_t)((0xFFFFFFFFu - rng) % rng_excl);
            while (leftover < threshold) {
                m = (uint64_t)next32() * (uint64_t)rng_excl;
                leftover = (uint32_t)m;
            }
        }
        return (uint32_t)(m >> 32);
    }
    uint64_t bounded(uint64_t rng) {
        if (rng == 0) return 0;
        return (uint64_t)lemire32((uint32_t)rng);
    }
};

static void seed_seq_1234(uint64_t out[4]) {
    const uint32_t INIT_A = 0x43b0d7e5u, MULT_A = 0x931e8875u;
    const uint32_t INIT_B = 0x8b51f9ddu, MULT_B = 0x58f38dedu;
    const uint32_t MIX_L  = 0xca01f9ddu, MIX_R  = 0x4973f715u;
    uint32_t pool[4] = {0, 0, 0, 0};
    uint32_t hc = INIT_A;
    auto hashmix = [&](uint32_t v) -> uint32_t {
        v ^= hc; hc *= MULT_A; v *= hc; v ^= v >> 16; return v;
    };
    auto mix = [](uint32_t x, uint32_t y, uint32_t ml, uint32_t mr) -> uint32_t {
        uint32_t r = x * ml - y * mr; r ^= r >> 16; return r;
    };
    for (int i = 0; i < 4; i++) pool[i] = hashmix(i < 1 ? 1234u : 0u);
    for (int s = 0; s < 4; s++)
        for (int d = 0; d < 4; d++)
            if (s != d) pool[d] = mix(pool[d], hashmix(pool[s]), MIX_L, MIX_R);
    uint32_t hb = INIT_B;
    uint32_t st[8];
    for (int i = 0; i < 8; i++) {
        uint32_t dv = pool[i & 3];
        dv ^= hb; hb *= MULT_B; dv *= hb; dv ^= dv >> 16;
        st[i] = dv;
    }
    for (int i = 0; i < 4; i++)
        out[i] = (uint64_t)st[2 * i] | ((uint64_t)st[2 * i + 1] << 32);
}

static Pcg64 make_rng() {
    uint64_t w[4]; seed_seq_1234(w);
    u128_t seed128 = ((u128_t)w[0] << 64) | (u128_t)w[1];
    u128_t inc128  = ((u128_t)w[2] << 64) | (u128_t)w[3];
    Pcg64 r; r.has32 = false; r.buf32 = 0;
    r.inc = (inc128 << 1) | (u128_t)1;
    r.state = 0;
    r.step();
    r.state += seed128;
    r.step();
    return r;
}

static void choice2of4(Pcg64& r, int& c, int& t) {
    const uint64_t EMPTY = ~0ull;
    uint64_t hs[4] = {EMPTY, EMPTY, EMPTY, EMPTY};
    int64_t idx[2];
    int ls = 0;
    for (int j = 2; j <= 3; j++) {
        uint64_t val = r.bounded((uint64_t)j);
        uint64_t loc = val & 3ull;
        while (hs[loc] != EMPTY && hs[loc] != val) loc = (loc + 1) & 3ull;
        if (hs[loc] == EMPTY) { hs[loc] = val; idx[ls] = (int64_t)val; }
        else {
            loc = (uint64_t)j & 3ull;
            while (hs[loc] != EMPTY) loc = (loc + 1) & 3ull;
            hs[loc] = (uint64_t)j; idx[ls] = j;
        }
        ls++;
    }
    uint64_t jj = r.bounded(1);
    int64_t tmp = idx[1]; idx[1] = idx[jj]; idx[jj] = tmp;
    c = (int)idx[0]; t = (int)idx[1];
}

static PlanArg build_plan() {
    Pcg64 r = make_rng();
    PlanArg plan; plan.n = 0;
    for (int l = 0; l < 2; l++) {
        int i = 0;
        while (i < 4) {
            double u = r.rnd();
            if (u > 0.3) {
                int g = (int)r.bounded(2);
                int w = (int)r.bounded(3);
                if (plan.n < 24) plan.ops[plan.n] = make_int4(0, g, w, l * 4 + i);
                plan.n++;
                i++;
            } else {
                int c, t; choice2of4(r, c, t);
                if (plan.n < 24) plan.ops[plan.n] = make_int4(1, c, t, 0);
                plan.n++;
            }
        }
    }
    if (plan.n > 24) plan.n = 24;
    return plan;
}

} // namespace nprng

// ---------------------------------------------------------------------------
// Ground truth: run the reference's _make_plan with the real numpy.
// ---------------------------------------------------------------------------
static bool try_interp(const char* interp, const char* spath, PlanArg& plan) {
    char cmd[1200];
    snprintf(cmd, sizeof(cmd), "'%s' '%s' 2>/dev/null", interp, spath);
    FILE* p = popen(cmd, "r");
    if (!p) return false;
    PlanArg tmp;
    long magic = 0;
    int n = -1;
    bool ok = (fscanf(p, "%ld", &magic) == 1) && magic == 987654321L;
    ok = ok && (fscanf(p, "%d", &n) == 1) && n >= 8 && n <= 24;
    if (ok) {
        tmp.n = n;
        for (int i = 0; i < n && ok; i++) {
            int a, b, c, d;
            ok = (fscanf(p, "%d %d %d %d", &a, &b, &c, &d) == 4);
            if (ok) tmp.ops[i] = make_int4(a, b, c, d);
        }
    }
    pclose(p);
    if (!ok) return false;
    int nrot = 0; bool valid = true;
    for (int i = 0; i < n; i++) {
        int4 o = tmp.ops[i];
        if (o.x == 0) {
            valid = valid && (o.y >= 0 && o.y <= 2) && (o.z >= 0 && o.z <= 3)
                          && (o.w == nrot);
            nrot++;
        } else if (o.x == 1) {
            valid = valid && (o.y >= 0 && o.y <= 3) && (o.z >= 0 && o.z <= 3)
                          && (o.y != o.z);
        } else valid = false;
    }
    valid = valid && (nrot == 8);
    if (valid) { plan = tmp; return true; }
    return false;
}

static bool plan_from_python(PlanArg& plan) {
    const char* tmpdir = getenv("TMPDIR");
    if (!tmpdir || !*tmpdir) tmpdir = "/tmp";
    char spath[512];
    snprintf(spath, sizeof(spath), "%s/qonv_plan_v4_67499706024572.py", tmpdir);
    FILE* f = fopen(spath, "w");
    if (!f) return false;
    fputs(
"import numpy as np\n"
"rng = np.random.default_rng(1234)\n"
"ops = []\n"
"for l in range(2):\n"
"    i = 0\n"
"    while i < 4:\n"
"        if rng.random() > 0.3:\n"
"            g = ('RX', 'RY', 'RZ')[int(rng.integers(3))]\n"
"            w = int(rng.integers(4))\n"
"            ops.append((0, {'RX': 0, 'RY': 1, 'RZ': 2}[g], w, l * 4 + i))\n"
"            i += 1\n"
"        else:\n"
"            c, t = rng.choice(4, size=2, replace=False)\n"
"            ops.append((1, int(c), int(t), 0))\n"
"print(987654321)\n"
"print(len(ops))\n"
"for o in ops:\n"
"    print(o[0], o[1], o[2], o[3])\n", f);
    fclose(f);

    char exe[600]; exe[0] = 0;
    ssize_t en = readlink("/proc/self/exe", exe, sizeof(exe) - 1);
    if (en > 0) exe[en] = 0; else exe[0] = 0;

    if (exe[0] && try_interp(exe, spath, plan)) return true;
    if (try_interp("python3", spath, plan)) return true;
    if (try_interp("python", spath, plan)) return true;
    if (try_interp("/usr/bin/python3", spath, plan)) return true;
    return false;
}

// ---------------------------------------------------------------------------
// Fused kernel. Grid: 2048 blocks x 256 threads; block = (b, c2, j<16).
//
// Phase 1 (per block, redundant): build G[81] for this block's weight set.
//   U evolution: threads 0..127 = (column = tid>>3, pair = tid&7), one
//   butterfly per thread per gate op, __syncthreads between ops.
//   Rs[p][q] = sum_r z_r Re(conj(U[r][p]) U[r][q]), z_r by wire0 (bit3).
//   G[e] = (1/16) sum_p sigma(p,e) Rs[p][p^mask(e)].
// Phase 2: lanes u=0..63 (wave 0, 100% active) compute the 64 active float4
//   cells (k=u>>2 <16, l4=u&3 <4): 8x float4 x-loads, 16 hw sin/cos
//   (REVOLUTION args), 4x 80-FMA Horner with G in 81 VGPRs. Results staged
//   in LDS.
// Phase 3: all 256 threads store 2 float4s each, fully coalesced: cell
//   (k=t>>3, l4=t&7) of active slice j (computed value or 0) and of zero
//   slice j+16.
// ---------------------------------------------------------------------------
__global__ void __launch_bounds__(256)
qonv_fused_kernel(const float* __restrict__ x, const float* __restrict__ w1,
                  const float* __restrict__ w2, float* __restrict__ out,
                  PlanArg plan, float diag) {
    const unsigned blk = blockIdx.x;            // 2048
    const int t  = (int)threadIdx.x;
    const int j  = (int)(blk & 15u);            // 0..15 (active j only)
    const int c2 = (int)((blk >> 4) & 31u);     // uniform per block
    const int b  = (int)(blk >> 9);             // uniform per block

    __shared__ float2 Amp[16][16];              // [column][row/state]
    __shared__ float Rs[256];
    __shared__ float Gs[81];
    __shared__ float4 Res[64];

    const float* W = (c2 >= 16) ? w2 : w1;

    // ---- Phase 1: build G ----
    // init U = I (one entry per thread)
    Amp[t >> 4][t & 15] = make_float2((t >> 4) == (t & 15) ? 1.f : 0.f, 0.f);
    __syncthreads();

    const int col = t >> 3;                     // 0..31 (valid for t<128)
    const int pr  = t & 7;                      // 0..7
    for (int o = 0; o < plan.n; o++) {
        int4 op = plan.ops[o];
        if (t < 128) {
            if (op.x == 0) {                    // rotation on wire op.z
                float th = W[op.w];
                float s, c; __sincosf(0.5f * th, &s, &c);
                int bit = 8 >> op.z;            // wire0 = bit3
                int low = bit - 1;
                int p = ((pr & ~low) << 1) | (pr & low);   // insert 0 at `bit`
                float2 a0 = Amp[col][p], a1 = Amp[col][p | bit];
                float2 n0, n1;
                if (op.y == 0) {                // RX [[c,-is],[-is,c]]
                    n0 = make_float2(c * a0.x + s * a1.y, c * a0.y - s * a1.x);
                    n1 = make_float2(s * a0.y + c * a1.x, -s * a0.x + c * a1.y);
                } else if (op.y == 1) {         // RY [[c,-s],[s,c]]
                    n0 = make_float2(c * a0.x - s * a1.x, c * a0.y - s * a1.y);
                    n1 = make_float2(s * a0.x + c * a1.x, s * a0.y + c * a1.y);
                } else {                        // RZ diag(c-is, c+is)
                    n0 = make_float2(c * a0.x + s * a0.y, c * a0.y - s * a0.x);
                    n1 = make_float2(c * a1.x - s * a1.y, c * a1.y + s * a1.x);
                }
                Amp[col][p] = n0; Amp[col][p | bit] = n1;
            } else {                            // CNOT ctrl=op.y tgt=op.z
                int cb = 8 >> op.y, tb = 8 >> op.z;
                int low = tb - 1;
                int p = ((pr & ~low) << 1) | (pr & low);   // tb clear
                if (p & cb) {
                    float2 t0 = Amp[col][p];
                    Amp[col][p] = Amp[col][p | tb];
                    Amp[col][p | tb] = t0;
                }
            }
        }
        __syncthreads();
    }

    {   // Rs: one entry per thread
        int p = t >> 4, q = t & 15;
        float acc = 0.f;
        #pragma unroll
        for (int r = 0; r < 16; r++) {
            float zr = (r & 8) ? -1.f : 1.f;
            float2 up = Amp[p][r], uq = Amp[q][r];
            acc += zr * (up.x * uq.x + up.y * uq.y);
        }
        Rs[t] = acc;
    }
    __syncthreads();

    if (t < 81) {
        int e = t;
        int dig[4];
        dig[3] = e % 3; dig[2] = (e / 3) % 3; dig[1] = (e / 9) % 3; dig[0] = e / 27;
        int mask = 0;
        #pragma unroll
        for (int q = 0; q < 4; q++) if (dig[q] == 2) mask |= (8 >> q);
        float acc = 0.f;
        for (int p = 0; p < 16; p++) {
            float sgn = 1.f;
            #pragma unroll
            for (int q = 0; q < 4; q++)
                if (dig[q] == 1 && (p & (8 >> q))) sgn = -sgn;
            acc += sgn * Rs[p * 16 + (p ^ mask)];
        }
        Gs[e] = acc * 0.0625f;
    }
    __syncthreads();

    // ---- Phase 2: compute 64 active float4 cells on wave 0 ----
    if (t < 64) {
        const int k  = t >> 2;                   // 0..15
        const int l4 = t & 3;                    // 0..3
        const int c = c2 & 15;
        const float* xc = x + (size_t)(b * 16 + c) * 262144u;   // 64*64*64
        const int J = 2 * j, K = 2 * k;
        const int off = 8 * l4;                  // float offset in 64-row
        const float* r00 = xc + ((J    ) * 64 + (K    )) * 64 + off;
        const float* r11 = xc + ((J + 1) * 64 + (K + 1)) * 64 + off;
        const float* r01 = xc + ((J    ) * 64 + (K + 1)) * 64 + off;
        const float* r10 = xc + ((J + 1) * 64 + (K    )) * 64 + off;
        // 8 floats per row: lo = elems 0..3, hi = elems 4..7 (16B-aligned)
        float4 a00 = *(const float4*)(r00), h00 = *(const float4*)(r00 + 4);
        float4 a11 = *(const float4*)(r11), h11 = *(const float4*)(r11 + 4);
        float4 a01 = *(const float4*)(r01), h01 = *(const float4*)(r01 + 4);
        float4 a10 = *(const float4*)(r10), h10 = *(const float4*)(r10 + 4);

        float Gr[81];
        #pragma unroll
        for (int i = 0; i < 81; i++) Gr[i] = Gs[i];

        // per-output wire inputs: outputs o=0..3 use row elements 2o (even)
        // or 2o+1 (odd). circuit1: y0=ev(J,K) y1=ev(J+1,K+1) y2=od(J,K+1)
        // y3=od(J+1,K). circuit2: y0=od(J+1,K+1) y1=od(J,K) y2=ev(J+1,K)
        // y3=ev(J,K+1).
        float Y0[4], Y1[4], Y2[4], Y3[4];
        if (c2 < 16) {
            Y0[0]=a00.x; Y0[1]=a00.z; Y0[2]=h00.x; Y0[3]=h00.z;
            Y1[0]=a11.x; Y1[1]=a11.z; Y1[2]=h11.x; Y1[3]=h11.z;
            Y2[0]=a01.y; Y2[1]=a01.w; Y2[2]=h01.y; Y2[3]=h01.w;
            Y3[0]=a10.y; Y3[1]=a10.w; Y3[2]=h10.y; Y3[3]=h10.w;
        } else {
            Y0[0]=a11.y; Y0[1]=a11.w; Y0[2]=h11.y; Y0[3]=h11.w;
            Y1[0]=a00.y; Y1[1]=a00.w; Y1[2]=h00.y; Y1[3]=h00.w;
            Y2[0]=a10.x; Y2[1]=a10.z; Y2[2]=h10.x; Y2[3]=h10.z;
            Y3[0]=a01.x; Y3[1]=a01.z; Y3[2]=h01.x; Y3[3]=h01.z;
        }

        float rr[4];
        #pragma unroll
        for (int o = 0; o < 4; o++) {
            float g0 = 0.5f * fminf(1.f, Y0[o]);   // revolutions
            float g1 = 0.5f * fminf(1.f, Y1[o]);
            float g2 = 0.5f * fminf(1.f, Y2[o]);
            float g3 = 0.5f * fminf(1.f, Y3[o]);
            float C0 = __builtin_amdgcn_cosf(g0), S0 = __builtin_amdgcn_sinf(g0);
            float C1 = __builtin_amdgcn_cosf(g1), S1 = __builtin_amdgcn_sinf(g1);
            float C2 = __builtin_amdgcn_cosf(g2), S2 = __builtin_amdgcn_sinf(g2);
            float C3 = __builtin_amdgcn_cosf(g3), S3 = __builtin_amdgcn_sinf(g3);

            float A[27];
            #pragma unroll
            for (int i = 0; i < 27; i++)
                A[i] = fmaf(S3, Gr[3 * i + 2], fmaf(C3, Gr[3 * i + 1], Gr[3 * i]));
            float Bv[9];
            #pragma unroll
            for (int i = 0; i < 9; i++)
                Bv[i] = fmaf(S2, A[3 * i + 2], fmaf(C2, A[3 * i + 1], A[3 * i]));
            float D[3];
            #pragma unroll
            for (int i = 0; i < 3; i++)
                D[i] = fmaf(S1, Bv[3 * i + 2], fmaf(C1, Bv[3 * i + 1], Bv[3 * i]));
            rr[o] = fmaf(S0, D[2], fmaf(C0, D[1], D[0]));
        }
        Res[t] = make_float4(rr[0], rr[1], rr[2], rr[3]);
    }
    __syncthreads();

    // ---- Phase 3: coalesced stores (2 float4 per thread) ----
    const int sk  = t >> 3;                      // 0..31
    const int sl4 = t & 7;                       // 0..7
    float4 val = make_float4(0.f, 0.f, 0.f, 0.f);
    if (sk < 16 && sl4 < 4) val = Res[(sk << 2) | sl4];
    if (blk == 0u && t == 0) val.x += diag;      // diagnostic sentinel

    // out float4 layout: (((b*32 + c2)*32 + j)*32 + k)*8 + l4
    float4* out4 = (float4*)out;
    const size_t base = ((size_t)((b * 32 + c2) * 32 + j)) * 256u
                        + (unsigned)(sk * 8 + sl4);
    out4[base] = val;                            // active slice j
    out4[base + 4096u] = make_float4(0.f, 0.f, 0.f, 0.f);   // zero slice j+16
}

// ---------------------------------------------------------------------------
extern "C" void kernel_launch(void* const* d_in, const int* in_sizes, int n_in,
                              void* d_out, int out_size, void* d_ws, size_t ws_size,
                              hipStream_t stream) {
    (void)in_sizes; (void)n_in; (void)out_size; (void)d_ws; (void)ws_size;
    const float* x  = (const float*)d_in[0];
    const float* w1 = (const float*)d_in[1];
    const float* w2 = (const float*)d_in[2];
    float* out = (float*)d_out;

    // Plan is a pure function of SEED=1234; computed once on the first
    // (pre-capture) call and cached -> identical GPU work every call.
    static PlanArg g_plan;
    static float g_diag = 0.f;
    static bool g_ready = false;
    if (!g_ready) {
        if (!plan_from_python(g_plan)) {
            g_plan = nprng::build_plan();
            g_diag = 1000.f;   // signal: python ground-truth path unavailable
        }
        g_ready = true;
    }

    // 4 (b) * 32 (c2) * 16 (active j) = 2048 blocks
    qonv_fused_kernel<<<dim3(2048), dim3(256), 0, stream>>>(
        x, w1, w2, out, g_plan, g_diag);
}

// Round 3
// 102.655 us; speedup vs baseline: 1.1371x; 1.1371x over previous
//
#include <hip/hip_runtime.h>
#include <stdint.h>
#include <stdio.h>
#include <stdlib.h>
#include <unistd.h>
#include <math.h>

// ============================================================================
// QonvLayer: out[b, c2, j, k, l] (4, 32, 32, 32, 32) fp32.
// Only j,k,l < 16 nonzero. c2<16 -> circuit(weights1) on patch offsets
// (0,0,0),(1,1,0),(0,1,1),(1,0,1); c2>=16 -> circuit(weights2) on offsets
// (1,1,1),(0,0,1),(1,0,0),(0,1,0). Input index = (2j+dj, 2k+dk, 2l+dl).
//
// value = <Z_0> = 81-coefficient double-angle form:
//   <Z_0> = sum_{e in {0,1,2}^4} G[e] * prod_t v_t[e_t],
//   v_t = (1, cos(pi*min(1,y_t)), sin(pi*min(1,y_t)))
// G built per weight set by a tiny 2-block kernel into a __device__ global.
//
// R6 (this round): revert R5's fusion (regressed +8us: the ~1.2us G-build
// barrier/LDS chain replicated into 2048 blocks serialized ~3-resident
// blocks/CU). Back to two kernels; main kernel restructured:
//  - 512 blocks x 256 threads, EVERY thread computes one active float4
//    (131,072 active cells exactly; 100% lane-activity; 2048 waves vs
//    R4's 16,384).
//  - Zero region folded in bijectively: active cell (j,k,m) also stores
//    zeros at {j,j+16}x{k,k+16}x{m,m+4}\{self} -> 7 extra dwordx4 stores,
//    full 16.8 MB output covered with no zero-only blocks.
//  - Algebra identical to the R3/R4-validated version (absmax 0.0039 pass).
//
// Gate plan = _make_plan(1234) via the harness's own python (/proc/self/exe)
// + numpy (ground truth, validated round 3); C++ PCG64 replication fallback
// (known-suspect; +1000 sentinel on out[0] if python unavailable).
// ============================================================================

struct PlanArg {
    int n;
    // ops[i]: x = type (0=rot, 1=cnot)
    //         y = gate (0 RX,1 RY,2 RZ)   or ctrl wire
    //         z = wire                    or tgt wire
    //         w = weight flat index l*4+i or 0
    int4 ops[24];
};

__device__ float g_G[2][81];   // 81-coeff tensor per weight set

// ---------------------------------------------------------------------------
// Fallback: host-side replication of numpy default_rng(1234) (emergency only)
// ---------------------------------------------------------------------------
typedef unsigned __int128 u128_t;

namespace nprng {

struct Pcg64 {
    u128_t state, inc;
    bool has32; uint32_t buf32;

    void step() {
        const u128_t MULT =
            ((u128_t)0x2360ed051fc65da4ULL << 64) | (u128_t)0x4385df649fccf645ULL;
        state = state * MULT + inc;
    }
    uint64_t next64() {
        step();
        uint64_t hi = (uint64_t)(state >> 64), lo = (uint64_t)state;
        unsigned rot = (unsigned)(hi >> 58);
        uint64_t v = hi ^ lo;
        return (v >> rot) | (v << ((64u - rot) & 63u));
    }
    uint32_t next32() {
        if (has32) { has32 = false; return buf32; }
        uint64_t n = next64();
        has32 = true; buf32 = (uint32_t)(n >> 32);
        return (uint32_t)n;
    }
    double rnd() {
        return (double)(next64() >> 11) * (1.0 / 9007199254740992.0);
    }
    uint32_t lemire32(uint32_t rng) {
        uint32_t rng_excl = rng + 1u;
        uint64_t m = (uint64_t)next32() * (uint64_t)rng_excl;
        uint32_t leftover = (uint32_t)m;
        if (leftover < rng_excl) {
            uint32_t threshold = (uint32_t)((0xFFFFFFFFu - rng) % rng_excl);
            while (leftover < threshold) {
                m = (uint64_t)next32() * (uint64_t)rng_excl;
                leftover = (uint32_t)m;
            }
        }
        return (uint32_t)(m >> 32);
    }
    uint64_t bounded(uint64_t rng) {
        if (rng == 0) return 0;
        return (uint64_t)lemire32((uint32_t)rng);
    }
};

static void seed_seq_1234(uint64_t out[4]) {
    const uint32_t INIT_A = 0x43b0d7e5u, MULT_A = 0x931e8875u;
    const uint32_t INIT_B = 0x8b51f9ddu, MULT_B = 0x58f38dedu;
    const uint32_t MIX_L  = 0xca01f9ddu, MIX_R  = 0x4973f715u;
    uint32_t pool[4] = {0, 0, 0, 0};
    uint32_t hc = INIT_A;
    auto hashmix = [&](uint32_t v) -> uint32_t {
        v ^= hc; hc *= MULT_A; v *= hc; v ^= v >> 16; return v;
    };
    auto mix = [](uint32_t x, uint32_t y, uint32_t ml, uint32_t mr) -> uint32_t {
        uint32_t r = x * ml - y * mr; r ^= r >> 16; return r;
    };
    for (int i = 0; i < 4; i++) pool[i] = hashmix(i < 1 ? 1234u : 0u);
    for (int s = 0; s < 4; s++)
        for (int d = 0; d < 4; d++)
            if (s != d) pool[d] = mix(pool[d], hashmix(pool[s]), MIX_L, MIX_R);
    uint32_t hb = INIT_B;
    uint32_t st[8];
    for (int i = 0; i < 8; i++) {
        uint32_t dv = pool[i & 3];
        dv ^= hb; hb *= MULT_B; dv *= hb; dv ^= dv >> 16;
        st[i] = dv;
    }
    for (int i = 0; i < 4; i++)
        out[i] = (uint64_t)st[2 * i] | ((uint64_t)st[2 * i + 1] << 32);
}

static Pcg64 make_rng() {
    uint64_t w[4]; seed_seq_1234(w);
    u128_t seed128 = ((u128_t)w[0] << 64) | (u128_t)w[1];
    u128_t inc128  = ((u128_t)w[2] << 64) | (u128_t)w[3];
    Pcg64 r; r.has32 = false; r.buf32 = 0;
    r.inc = (inc128 << 1) | (u128_t)1;
    r.state = 0;
    r.step();
    r.state += seed128;
    r.step();
    return r;
}

static void choice2of4(Pcg64& r, int& c, int& t) {
    const uint64_t EMPTY = ~0ull;
    uint64_t hs[4] = {EMPTY, EMPTY, EMPTY, EMPTY};
    int64_t idx[2];
    int ls = 0;
    for (int j = 2; j <= 3; j++) {
        uint64_t val = r.bounded((uint64_t)j);
        uint64_t loc = val & 3ull;
        while (hs[loc] != EMPTY && hs[loc] != val) loc = (loc + 1) & 3ull;
        if (hs[loc] == EMPTY) { hs[loc] = val; idx[ls] = (int64_t)val; }
        else {
            loc = (uint64_t)j & 3ull;
            while (hs[loc] != EMPTY) loc = (loc + 1) & 3ull;
            hs[loc] = (uint64_t)j; idx[ls] = j;
        }
        ls++;
    }
    uint64_t jj = r.bounded(1);
    int64_t tmp = idx[1]; idx[1] = idx[jj]; idx[jj] = tmp;
    c = (int)idx[0]; t = (int)idx[1];
}

static PlanArg build_plan() {
    Pcg64 r = make_rng();
    PlanArg plan; plan.n = 0;
    for (int l = 0; l < 2; l++) {
        int i = 0;
        while (i < 4) {
            double u = r.rnd();
            if (u > 0.3) {
                int g = (int)r.bounded(2);
                int w = (int)r.bounded(3);
                if (plan.n < 24) plan.ops[plan.n] = make_int4(0, g, w, l * 4 + i);
                plan.n++;
                i++;
            } else {
                int c, t; choice2of4(r, c, t);
                if (plan.n < 24) plan.ops[plan.n] = make_int4(1, c, t, 0);
                plan.n++;
            }
        }
    }
    if (plan.n > 24) plan.n = 24;
    return plan;
}

} // namespace nprng

// ---------------------------------------------------------------------------
// Ground truth: run the reference's _make_plan with the real numpy.
// ---------------------------------------------------------------------------
static bool try_interp(const char* interp, const char* spath, PlanArg& plan) {
    char cmd[1200];
    snprintf(cmd, sizeof(cmd), "'%s' '%s' 2>/dev/null", interp, spath);
    FILE* p = popen(cmd, "r");
    if (!p) return false;
    PlanArg tmp;
    long magic = 0;
    int n = -1;
    bool ok = (fscanf(p, "%ld", &magic) == 1) && magic == 987654321L;
    ok = ok && (fscanf(p, "%d", &n) == 1) && n >= 8 && n <= 24;
    if (ok) {
        tmp.n = n;
        for (int i = 0; i < n && ok; i++) {
            int a, b, c, d;
            ok = (fscanf(p, "%d %d %d %d", &a, &b, &c, &d) == 4);
            if (ok) tmp.ops[i] = make_int4(a, b, c, d);
        }
    }
    pclose(p);
    if (!ok) return false;
    int nrot = 0; bool valid = true;
    for (int i = 0; i < n; i++) {
        int4 o = tmp.ops[i];
        if (o.x == 0) {
            valid = valid && (o.y >= 0 && o.y <= 2) && (o.z >= 0 && o.z <= 3)
                          && (o.w == nrot);
            nrot++;
        } else if (o.x == 1) {
            valid = valid && (o.y >= 0 && o.y <= 3) && (o.z >= 0 && o.z <= 3)
                          && (o.y != o.z);
        } else valid = false;
    }
    valid = valid && (nrot == 8);
    if (valid) { plan = tmp; return true; }
    return false;
}

static bool plan_from_python(PlanArg& plan) {
    const char* tmpdir = getenv("TMPDIR");
    if (!tmpdir || !*tmpdir) tmpdir = "/tmp";
    char spath[512];
    snprintf(spath, sizeof(spath), "%s/qonv_plan_v4_67499706024572.py", tmpdir);
    FILE* f = fopen(spath, "w");
    if (!f) return false;
    fputs(
"import numpy as np\n"
"rng = np.random.default_rng(1234)\n"
"ops = []\n"
"for l in range(2):\n"
"    i = 0\n"
"    while i < 4:\n"
"        if rng.random() > 0.3:\n"
"            g = ('RX', 'RY', 'RZ')[int(rng.integers(3))]\n"
"            w = int(rng.integers(4))\n"
"            ops.append((0, {'RX': 0, 'RY': 1, 'RZ': 2}[g], w, l * 4 + i))\n"
"            i += 1\n"
"        else:\n"
"            c, t = rng.choice(4, size=2, replace=False)\n"
"            ops.append((1, int(c), int(t), 0))\n"
"print(987654321)\n"
"print(len(ops))\n"
"for o in ops:\n"
"    print(o[0], o[1], o[2], o[3])\n", f);
    fclose(f);

    char exe[600]; exe[0] = 0;
    ssize_t en = readlink("/proc/self/exe", exe, sizeof(exe) - 1);
    if (en > 0) exe[en] = 0; else exe[0] = 0;

    if (exe[0] && try_interp(exe, spath, plan)) return true;
    if (try_interp("python3", spath, plan)) return true;
    if (try_interp("python", spath, plan)) return true;
    if (try_interp("/usr/bin/python3", spath, plan)) return true;
    return false;
}

// ---------------------------------------------------------------------------
// Kernel 1: build G[set][81]. 2 blocks x 128 threads (one block per set).
// Butterfly-parallel evolution: thread = (column = tid>>3, pair = tid&7).
// For each gate op, the 16 states of a column split into 8 independent
// (p, p|bit) pairs -> 128 parallel butterflies, one __syncthreads per op.
// Step B: R[p][q] = sum_r z_r Re(conj(U[r][p]) U[r][q]), z_r by wire0 (bit3).
// Step C: G[e] = (1/16) sum_p sigma(p,e) R[p][p^mask(e)].
// (Validated structure from R4/R1 — do NOT fuse into the main kernel: R5
// showed the barrier/LDS chain replicated per-block costs +8us.)
// ---------------------------------------------------------------------------
__global__ void build_G_kernel(const float* __restrict__ w1,
                               const float* __restrict__ w2, PlanArg plan) {
    const int set = blockIdx.x;
    const float* W = (set == 0) ? w1 : w2;
    const int tid = threadIdx.x;          // 0..127
    const int col = tid >> 3;             // 0..15  (column of U)
    const int pr  = tid & 7;              // 0..7   (pair index within column)

    __shared__ float2 Amp[16][16];        // [column][row/state]
    __shared__ float Rs[256];

    // init U = I
    for (int e = tid; e < 256; e += 128)
        Amp[e >> 4][e & 15] = make_float2((e >> 4) == (e & 15) ? 1.f : 0.f, 0.f);
    __syncthreads();

    for (int o = 0; o < plan.n; o++) {
        int4 op = plan.ops[o];
        if (op.x == 0) {                  // rotation on wire op.z
            float th = W[op.w];
            float s, c; __sincosf(0.5f * th, &s, &c);
            int bit = 8 >> op.z;          // wire0 = bit3
            int low = bit - 1;
            int p = ((pr & ~low) << 1) | (pr & low);   // insert 0 at `bit`
            float2 a0 = Amp[col][p], a1 = Amp[col][p | bit];
            float2 n0, n1;
            if (op.y == 0) {              // RX [[c,-is],[-is,c]]
                n0 = make_float2(c * a0.x + s * a1.y, c * a0.y - s * a1.x);
                n1 = make_float2(s * a0.y + c * a1.x, -s * a0.x + c * a1.y);
            } else if (op.y == 1) {       // RY [[c,-s],[s,c]]
                n0 = make_float2(c * a0.x - s * a1.x, c * a0.y - s * a1.y);
                n1 = make_float2(s * a0.x + c * a1.x, s * a0.y + c * a1.y);
            } else {                      // RZ diag(c-is, c+is)
                n0 = make_float2(c * a0.x + s * a0.y, c * a0.y - s * a0.x);
                n1 = make_float2(c * a1.x - s * a1.y, c * a1.y + s * a1.x);
            }
            Amp[col][p] = n0; Amp[col][p | bit] = n1;
        } else {                          // CNOT ctrl=op.y tgt=op.z
            int cb = 8 >> op.y, tb = 8 >> op.z;
            int low = tb - 1;
            int p = ((pr & ~low) << 1) | (pr & low);   // tb clear
            if (p & cb) {
                float2 t0 = Amp[col][p];
                Amp[col][p] = Amp[col][p | tb];
                Amp[col][p | tb] = t0;
            }
        }
        __syncthreads();
    }

    for (int e = tid; e < 256; e += 128) {
        int p = e >> 4, q = e & 15;
        float acc = 0.f;
        #pragma unroll
        for (int r = 0; r < 16; r++) {
            float zr = (r & 8) ? -1.f : 1.f;
            float2 up = Amp[p][r], uq = Amp[q][r];
            acc += zr * (up.x * uq.x + up.y * uq.y);
        }
        Rs[e] = acc;
    }
    __syncthreads();

    for (int e = tid; e < 81; e += 128) {
        int dig[4];
        dig[3] = e % 3; dig[2] = (e / 3) % 3; dig[1] = (e / 9) % 3; dig[0] = e / 27;
        int mask = 0;
        #pragma unroll
        for (int t = 0; t < 4; t++) if (dig[t] == 2) mask |= (8 >> t);
        float acc = 0.f;
        for (int p = 0; p < 16; p++) {
            float sgn = 1.f;
            #pragma unroll
            for (int t = 0; t < 4; t++)
                if (dig[t] == 1 && (p & (8 >> t))) sgn = -sgn;
            acc += sgn * Rs[p * 16 + (p ^ mask)];
        }
        g_G[set][e] = acc * 0.0625f;
    }
}

// ---------------------------------------------------------------------------
// Kernel 2: main. 512 blocks x 256 threads. EVERY thread computes exactly one
// active float4 cell (100% lane-activity; 2048 waves total).
//
// Active cell enumeration g = blk*256 + t over (b, c2, j<16, k<16, l4<4):
//   l4 = t&3, k = (t>>2)&15, j = ((blk&3)<<2)|(t>>6),
//   c2 = (blk>>2)&31, b = blk>>7.
// Each wave has uniform j; lanes cover (k, l4) -> stores are 64B-sector
// dense (4 consecutive lanes per contiguous 64B sector).
//
// Zero region folded in bijectively: cell (j,k,m) also stores zeros at the
// 7 cells {j,j+16}x{k,k+16}x{m,m+4}\{self} -> whole (32,32,8)-float4 slice
// covered exactly once.
//
// Per thread: 8x float4 x-loads, 16 hw sin/cos (REVOLUTION args), 4x 80-FMA
// Horner with G in 81 VGPRs (from LDS broadcast).
// ---------------------------------------------------------------------------
__global__ void __launch_bounds__(256)
qonv_a_kernel(const float* __restrict__ x, float* __restrict__ out, float diag) {
    const unsigned blk = blockIdx.x;            // 512
    const int t  = (int)threadIdx.x;
    const int c2 = (int)((blk >> 2) & 31u);     // uniform per block
    const int b  = (int)(blk >> 7);             // uniform per block

    __shared__ float Gs[81];
    if (t < 81) Gs[t] = g_G[c2 >= 16 ? 1 : 0][t];
    __syncthreads();

    const int l4 = t & 3;                       // 0..3
    const int k  = (t >> 2) & 15;               // 0..15
    const int j  = (int)((blk & 3u) << 2) | (t >> 6);   // 0..15, wave-uniform

    const int c = c2 & 15;
    const float* xc = x + (size_t)(b * 16 + c) * 262144u;   // 64*64*64
    const int J = 2 * j, K = 2 * k;
    const int off = 8 * l4;                     // float offset in 64-row
    const float* r00 = xc + ((J    ) * 64 + (K    )) * 64 + off;
    const float* r11 = xc + ((J + 1) * 64 + (K + 1)) * 64 + off;
    const float* r01 = xc + ((J    ) * 64 + (K + 1)) * 64 + off;
    const float* r10 = xc + ((J + 1) * 64 + (K    )) * 64 + off;
    // 8 floats per row: lo = elems 0..3, hi = elems 4..7 (16B-aligned)
    float4 a00 = *(const float4*)(r00), h00 = *(const float4*)(r00 + 4);
    float4 a11 = *(const float4*)(r11), h11 = *(const float4*)(r11 + 4);
    float4 a01 = *(const float4*)(r01), h01 = *(const float4*)(r01 + 4);
    float4 a10 = *(const float4*)(r10), h10 = *(const float4*)(r10 + 4);

    float Gr[81];
    #pragma unroll
    for (int i = 0; i < 81; i++) Gr[i] = Gs[i];

    // per-output wire inputs: outputs o=0..3 use row elements 2o (even)
    // or 2o+1 (odd). circuit1: y0=ev(J,K) y1=ev(J+1,K+1) y2=od(J,K+1)
    // y3=od(J+1,K). circuit2: y0=od(J+1,K+1) y1=od(J,K) y2=ev(J+1,K)
    // y3=ev(J,K+1).
    float Y0[4], Y1[4], Y2[4], Y3[4];
    if (c2 < 16) {
        Y0[0]=a00.x; Y0[1]=a00.z; Y0[2]=h00.x; Y0[3]=h00.z;
        Y1[0]=a11.x; Y1[1]=a11.z; Y1[2]=h11.x; Y1[3]=h11.z;
        Y2[0]=a01.y; Y2[1]=a01.w; Y2[2]=h01.y; Y2[3]=h01.w;
        Y3[0]=a10.y; Y3[1]=a10.w; Y3[2]=h10.y; Y3[3]=h10.w;
    } else {
        Y0[0]=a11.y; Y0[1]=a11.w; Y0[2]=h11.y; Y0[3]=h11.w;
        Y1[0]=a00.y; Y1[1]=a00.w; Y1[2]=h00.y; Y1[3]=h00.w;
        Y2[0]=a10.x; Y2[1]=a10.z; Y2[2]=h10.x; Y2[3]=h10.z;
        Y3[0]=a01.x; Y3[1]=a01.z; Y3[2]=h01.x; Y3[3]=h01.z;
    }

    float rr[4];
    #pragma unroll
    for (int o = 0; o < 4; o++) {
        float g0 = 0.5f * fminf(1.f, Y0[o]);   // revolutions
        float g1 = 0.5f * fminf(1.f, Y1[o]);
        float g2 = 0.5f * fminf(1.f, Y2[o]);
        float g3 = 0.5f * fminf(1.f, Y3[o]);
        float C0 = __builtin_amdgcn_cosf(g0), S0 = __builtin_amdgcn_sinf(g0);
        float C1 = __builtin_amdgcn_cosf(g1), S1 = __builtin_amdgcn_sinf(g1);
        float C2 = __builtin_amdgcn_cosf(g2), S2 = __builtin_amdgcn_sinf(g2);
        float C3 = __builtin_amdgcn_cosf(g3), S3 = __builtin_amdgcn_sinf(g3);

        float A[27];
        #pragma unroll
        for (int i = 0; i < 27; i++)
            A[i] = fmaf(S3, Gr[3 * i + 2], fmaf(C3, Gr[3 * i + 1], Gr[3 * i]));
        float Bv[9];
        #pragma unroll
        for (int i = 0; i < 9; i++)
            Bv[i] = fmaf(S2, A[3 * i + 2], fmaf(C2, A[3 * i + 1], A[3 * i]));
        float D[3];
        #pragma unroll
        for (int i = 0; i < 3; i++)
            D[i] = fmaf(S1, Bv[3 * i + 2], fmaf(C1, Bv[3 * i + 1], Bv[3 * i]));
        rr[o] = fmaf(S0, D[2], fmaf(C0, D[1], D[0]));
    }
    float4 val = make_float4(rr[0], rr[1], rr[2], rr[3]);
    if (blk == 0u && t == 0) val.x += diag;     // diagnostic sentinel

    // out float4 layout: (((b*32 + c2)*32 + j)*32 + k)*8 + m
    float4* out4 = (float4*)out;
    const size_t base = ((size_t)((b * 32 + c2) * 32 + j)) * 256u
                        + (unsigned)(k * 8 + l4);
    const float4 z = make_float4(0.f, 0.f, 0.f, 0.f);
    out4[base] = val;                 // (j,   k,    m  ) active
    out4[base + 4u] = z;              // (j,   k,    m+4)
    out4[base + 128u] = z;            // (j,   k+16, m  )
    out4[base + 132u] = z;            // (j,   k+16, m+4)
    out4[base + 4096u] = z;           // (j+16,k,    m  )
    out4[base + 4100u] = z;           // (j+16,k,    m+4)
    out4[base + 4224u] = z;           // (j+16,k+16, m  )
    out4[base + 4228u] = z;           // (j+16,k+16, m+4)
}

// ---------------------------------------------------------------------------
extern "C" void kernel_launch(void* const* d_in, const int* in_sizes, int n_in,
                              void* d_out, int out_size, void* d_ws, size_t ws_size,
                              hipStream_t stream) {
    (void)in_sizes; (void)n_in; (void)out_size; (void)d_ws; (void)ws_size;
    const float* x  = (const float*)d_in[0];
    const float* w1 = (const float*)d_in[1];
    const float* w2 = (const float*)d_in[2];
    float* out = (float*)d_out;

    // Plan is a pure function of SEED=1234; computed once on the first
    // (pre-capture) call and cached -> identical GPU work every call.
    static PlanArg g_plan;
    static float g_diag = 0.f;
    static bool g_ready = false;
    if (!g_ready) {
        if (!plan_from_python(g_plan)) {
            g_plan = nprng::build_plan();
            g_diag = 1000.f;   // signal: python ground-truth path unavailable
        }
        g_ready = true;
    }

    build_G_kernel<<<dim3(2), dim3(128), 0, stream>>>(w1, w2, g_plan);

    // 4 (b) * 32 (c2) * 4 (j-high) = 512 blocks; all threads active
    qonv_a_kernel<<<dim3(512), dim3(256), 0, stream>>>(x, out, g_diag);
}